// Round 8
// baseline (191.118 us; speedup 1.0000x reference)
//
#include <hip/hip_runtime.h>
#include <hip/hip_bf16.h>

#define GAMMA 0.9865f

typedef __attribute__((ext_vector_type(8))) short bf16x8;
typedef __attribute__((ext_vector_type(4))) float f32x4;
typedef __attribute__((ext_vector_type(2))) unsigned int u32x2;

static constexpr int Bb  = 8;
static constexpr int Tt  = 2048;
static constexpr int DIN = 1024;
static constexpr int Dd  = 1024;
static constexpr int Mm  = Bb * Tt;      // 16384
static constexpr int CL  = 64;           // chunk length for scan
static constexpr int NC  = Tt / CL;      // 32 chunks
static constexpr int NT  = DIN / 64;     // 16 K-tiles of BK=64

__device__ __forceinline__ void gload16(const void* g, void* l) {
  __builtin_amdgcn_global_load_lds(
      (const __attribute__((address_space(1))) void*)g,
      (__attribute__((address_space(3))) void*)l, 16, 0, 0);
}

__device__ __forceinline__ void bar() {
  asm volatile("" ::: "memory");
  __builtin_amdgcn_s_barrier();
  asm volatile("" ::: "memory");
}

__device__ __forceinline__ float bflo(unsigned int u) {
  return __uint_as_float((u & 0xffffu) << 16);
}
__device__ __forceinline__ float bfhi(unsigned int u) {
  return __uint_as_float(u & 0xffff0000u);
}

// ---- K1a: wsum[d] = sum_e Wk[d][e] --------------------------------------
__global__ void wsum_kernel(const float* __restrict__ Wk, float* __restrict__ wsum) {
  int row  = blockIdx.x * 4 + (threadIdx.x >> 6);
  int lane = threadIdx.x & 63;
  const float4* rp = (const float4*)(Wk + (size_t)row * DIN);
  float s = 0.f;
#pragma unroll
  for (int i = 0; i < 4; ++i) {
    float4 v = rp[lane + i * 64];
    s += v.x + v.y + v.z + v.w;
  }
  for (int off = 32; off; off >>= 1) s += __shfl_down(s, off);
  if (lane == 0) wsum[row] = s;
}

// ---- K1b: Wt[n][k] = bf16(W[k][n]) for Wq and Wv -------------------------
__global__ void wt_kernel(const float* __restrict__ Wq, const float* __restrict__ Wv,
                          __hip_bfloat16* __restrict__ Wt) {
  const float* W = blockIdx.z ? Wv : Wq;
  __hip_bfloat16* outp = Wt + (size_t)blockIdx.z * DIN * Dd;
  __shared__ float tile[32][33];
  int k0 = blockIdx.x * 32, n0 = blockIdx.y * 32;
  int tx = threadIdx.x, ty = threadIdx.y;  // (32,8)
#pragma unroll
  for (int i = 0; i < 4; ++i)
    tile[ty + i * 8][tx] = W[(size_t)(k0 + ty + i * 8) * Dd + n0 + tx];
  __syncthreads();
#pragma unroll
  for (int i = 0; i < 4; ++i)
    outp[(size_t)(n0 + ty + i * 8) * DIN + k0 + tx] =
        __float2bfloat16(tile[tx][ty + i * 8]);
}

// ---- K2: cast fp32 -> bf16, nontemporal, 64B read / 32B write per thread -
__global__ __launch_bounds__(256) void cast_kernel(
    const float* __restrict__ xq, const float* __restrict__ xv,
    __hip_bfloat16* __restrict__ oq, __hip_bfloat16* __restrict__ ov) {
  const float* src = blockIdx.y ? xv : xq;
  __hip_bfloat16* dst = blockIdx.y ? ov : oq;
  size_t i = (size_t)blockIdx.x * 256 + threadIdx.x;  // 16-float group
  const f32x4* p = (const f32x4*)src + i * 4;
  f32x4 f[4];
#pragma unroll
  for (int j = 0; j < 4; ++j) f[j] = __builtin_nontemporal_load(p + j);
  bf16x8* q = (bf16x8*)dst + i * 2;
#pragma unroll
  for (int h = 0; h < 2; ++h) {
    union { __hip_bfloat16 b[8]; bf16x8 v; } u;
#pragma unroll
    for (int j = 0; j < 8; ++j) u.b[j] = __float2bfloat16(f[h * 2 + j / 4][j & 3]);
    __builtin_nontemporal_store(u.v, q + h);
  }
}

// ---- K3: 256x256 8-phase bf16 MFMA GEMM, persistent x2 by-tiles ----------
// grid 256 = 1 block/CU, one round; each block does by = byp*2 + rep,
// rep 0,1 sharing the A panel. rep-1 prologue issued right after rep-0
// epilogue stores (HBM latency hides under store retire). K-loop body is
// the R3/R7-verified schedule (conflicts=0, counted vmcnt(4)/tile).

__device__ __forceinline__ void stage_half(const __hip_bfloat16* g, char* l, int tid) {
#pragma unroll
  for (int j = 0; j < 2; ++j) {
    int c = tid + j * 512;
    int row = c >> 3, ch = c & 7;
    gload16(g + (size_t)row * DIN + ((ch ^ (row & 7)) << 3), l + c * 16);
  }
}

__device__ __forceinline__ bf16x8 lds_frag(const char* base, int row, int kc) {
  return *(const bf16x8*)(base + (((row << 3) + (kc ^ (row & 7))) << 4));
}

#define MFMA_QUAD(MLO, NLO)                                                  \
  _Pragma("unroll") for (int mi = 0; mi < 4; ++mi)                           \
  _Pragma("unroll") for (int ni = 0; ni < 2; ++ni)                           \
  _Pragma("unroll") for (int ks = 0; ks < 2; ++ks)                           \
      acc[(MLO) + mi][(NLO) + ni] = __builtin_amdgcn_mfma_f32_16x16x32_bf16( \
          a[(MLO) + mi][ks], b[(NLO) + ni][ks], acc[(MLO) + mi][(NLO) + ni], 0, 0, 0);

__global__ __launch_bounds__(512, 2) void gemm8_kernel(
    const __hip_bfloat16* __restrict__ Aq, const __hip_bfloat16* __restrict__ Av,
    const __hip_bfloat16* __restrict__ Wt,
    __hip_bfloat16* __restrict__ Qbf, __hip_bfloat16* __restrict__ Vbf) {
  extern __shared__ char lds[];  // [2][A 32KB | B 32KB]

  // XCD-bijective swizzle: 256 blocks, 256 % 8 == 0 (chunk = 32/XCD)
  int lin = blockIdx.x;
  int wg  = (lin & 7) * 32 + (lin >> 3);
  int z   = wg >> 7, rem = wg & 127;
  int byp = rem & 1, bx = rem >> 1;

  const __hip_bfloat16* Ab = z ? Av : Aq;
  const int m0 = bx * 256;
  const __hip_bfloat16* Ag = Ab + (size_t)m0 * DIN;
  __hip_bfloat16* Cc = z ? Vbf : Qbf;

  const int tid = threadIdx.x;
  const int wv = tid >> 6, lane = tid & 63;
  const int wm = (wv >> 2) * 128, wn = (wv & 3) * 64;
  const int fq = lane >> 4, fr = lane & 15;

  // initial prologue (rep 0): A(0)->buf0, B(0)->buf0, A(1)->buf1
  {
    const __hip_bfloat16* Bg0 = Wt + ((size_t)z * Dd + (size_t)byp * 512) * DIN;
    stage_half(Ag,                  lds,                 tid);
    stage_half(Ag + 128 * DIN,      lds + 16384,         tid);
    stage_half(Bg0,                 lds + 32768,         tid);
    stage_half(Bg0 + 128 * DIN,     lds + 49152,         tid);
    stage_half(Ag + 64,             lds + 65536,         tid);
    stage_half(Ag + 128 * DIN + 64, lds + 65536 + 16384, tid);
    asm volatile("s_waitcnt vmcnt(4)" ::: "memory");
    bar();
  }

  for (int rep = 0; rep < 2; ++rep) {
    const int n0 = (byp * 2 + rep) * 256;
    const __hip_bfloat16* Bg = Wt + ((size_t)z * Dd + n0) * DIN;
    f32x4 acc[8][4] = {};

    for (int t = 0; t < NT; ++t) {
      char* buf  = lds + (t & 1) * 65536;
      char* bufN = lds + ((t + 1) & 1) * 65536;
      const char* At = buf;
      const char* Bt = buf + 32768;
      bf16x8 a[8][2], b[4][2];

      // ---- P0: read a[0..3], b[0..1]; stage B(t+1)h0
#pragma unroll
      for (int mi = 0; mi < 4; ++mi)
#pragma unroll
        for (int ks = 0; ks < 2; ++ks)
          a[mi][ks] = lds_frag(At, wm + mi * 16 + fr, ks * 4 + fq);
#pragma unroll
      for (int ni = 0; ni < 2; ++ni)
#pragma unroll
        for (int ks = 0; ks < 2; ++ks)
          b[ni][ks] = lds_frag(Bt, wn + ni * 16 + fr, ks * 4 + fq);
      if (t + 1 < NT) stage_half(Bg + (size_t)(t + 1) * 64, bufN + 32768, tid);
      bar();
      __builtin_amdgcn_s_setprio(1);
      MFMA_QUAD(0, 0);
      __builtin_amdgcn_s_setprio(0);
      bar();

      // ---- P1: read a[4..7]; stage B(t+1)h1
#pragma unroll
      for (int mi = 4; mi < 8; ++mi)
#pragma unroll
        for (int ks = 0; ks < 2; ++ks)
          a[mi][ks] = lds_frag(At, wm + mi * 16 + fr, ks * 4 + fq);
      if (t + 1 < NT)
        stage_half(Bg + 128 * DIN + (size_t)(t + 1) * 64, bufN + 49152, tid);
      bar();
      __builtin_amdgcn_s_setprio(1);
      MFMA_QUAD(4, 0);
      __builtin_amdgcn_s_setprio(0);
      bar();

      // ---- P2: read b[2..3]; stage A(t+2)h0 into buf (A dead after P1)
#pragma unroll
      for (int ni = 2; ni < 4; ++ni)
#pragma unroll
        for (int ks = 0; ks < 2; ++ks)
          b[ni][ks] = lds_frag(Bt, wn + ni * 16 + fr, ks * 4 + fq);
      if (t + 2 < NT) stage_half(Ag + (size_t)(t + 2) * 64, buf, tid);
      bar();
      __builtin_amdgcn_s_setprio(1);
      MFMA_QUAD(0, 2);
      __builtin_amdgcn_s_setprio(0);
      bar();

      // ---- P3: stage A(t+2)h1; counted vmcnt once per tile (T4)
      if (t + 2 < NT)
        stage_half(Ag + 128 * DIN + (size_t)(t + 2) * 64, buf + 16384, tid);
      if (t + 1 < NT) {
        if (t + 2 < NT) asm volatile("s_waitcnt vmcnt(4)" ::: "memory");
        else            asm volatile("s_waitcnt vmcnt(0)" ::: "memory");
      }
      bar();
      __builtin_amdgcn_s_setprio(1);
      MFMA_QUAD(4, 2);
      __builtin_amdgcn_s_setprio(0);
      bar();
    }

    // epilogue: C/D layout col=lane&15, row=(lane>>4)*4+reg
#pragma unroll
    for (int mi = 0; mi < 8; ++mi) {
#pragma unroll
      for (int ni = 0; ni < 4; ++ni) {
        f32x4 v = acc[mi][ni];
        int row = m0 + wm + mi * 16 + fq * 4;
        int col = n0 + wn + ni * 16 + fr;
#pragma unroll
        for (int j = 0; j < 4; ++j)
          Cc[(size_t)(row + j) * Dd + col] = __float2bfloat16(v[j]);
      }
    }

    // rep-1 prologue: issued after stores; vmcnt(4) leaves A(1) in flight
    if (rep == 0) {
      const __hip_bfloat16* Bg1 = Wt + ((size_t)z * Dd + (size_t)(byp * 2 + 1) * 256) * DIN;
      stage_half(Ag,                  lds,                 tid);
      stage_half(Ag + 128 * DIN,      lds + 16384,         tid);
      stage_half(Bg1,                 lds + 32768,         tid);
      stage_half(Bg1 + 128 * DIN,     lds + 49152,         tid);
      stage_half(Ag + 64,             lds + 65536,         tid);
      stage_half(Ag + 128 * DIN + 64, lds + 65536 + 16384, tid);
      asm volatile("s_waitcnt vmcnt(4)" ::: "memory");
      bar();
    }
  }
}

// ---- K4: ksum[i] = dot(xk[i,:], wsum) fp32 ------------------------------
__global__ void ksum_kernel(const float* __restrict__ xk, const float* __restrict__ wsum,
                            float* __restrict__ ksum) {
  int row  = blockIdx.x * 4 + (threadIdx.x >> 6);
  int lane = threadIdx.x & 63;
  const f32x4* rp = (const f32x4*)(xk + (size_t)row * DIN);
  const float4* wp = (const float4*)wsum;
  float s = 0.f;
#pragma unroll
  for (int i = 0; i < 4; ++i) {
    f32x4 a = __builtin_nontemporal_load(rp + lane + i * 64);
    float4 w = wp[lane + i * 64];
    s += a[0] * w.x + a[1] * w.y + a[2] * w.z + a[3] * w.w;
  }
  for (int off = 32; off; off >>= 1) s += __shfl_down(s, off);
  if (lane == 0) ksum[row] = s;
}

// ---- K5: per-chunk local scan end values E[b][c][d0..d0+3] --------------
__global__ __launch_bounds__(256) void scanA_kernel(
    const __hip_bfloat16* __restrict__ Vbf, const float* __restrict__ ksum,
    float* __restrict__ E) {
  int b = blockIdx.x, c = blockIdx.y;
  int d0 = threadIdx.x * 4;
  const __hip_bfloat16* Vp = Vbf + ((size_t)(b * Tt + c * CL) * Dd) + d0;
  const float* kp = ksum + b * Tt + c * CL;
  float s0 = 0.f, s1 = 0.f, s2 = 0.f, s3 = 0.f;
#pragma unroll 4
  for (int t = 0; t < CL; ++t) {
    u32x2 r = __builtin_nontemporal_load((const u32x2*)(Vp + (size_t)t * Dd));
    float kv = kp[t];
    if (c == 0 && t == 0) kv = 0.f;
    s0 = s0 * GAMMA + kv * bflo(r.x);
    s1 = s1 * GAMMA + kv * bfhi(r.x);
    s2 = s2 * GAMMA + kv * bflo(r.y);
    s3 = s3 * GAMMA + kv * bfhi(r.y);
  }
  f32x4 e; e[0] = s0; e[1] = s1; e[2] = s2; e[3] = s3;
  *(f32x4*)(E + ((size_t)b * NC + c) * Dd + d0) = e;
}

// ---- K6: compose carries across chunks ----------------------------------
__global__ void scanB_kernel(const float* __restrict__ E, float* __restrict__ carry,
                             float gCL) {
  int b = blockIdx.x;
  int d = blockIdx.y * 256 + threadIdx.x;
  float send = 0.f;
  for (int c = 0; c < NC; ++c) {
    size_t idx = ((size_t)b * NC + c) * Dd + d;
    float e = E[idx];
    carry[idx] = send;          // S at end of chunk c-1
    send = e + gCL * send;
  }
}

// ---- K7: final scan with carry, out = Q * S -----------------------------
__global__ __launch_bounds__(256) void final_kernel(
    const __hip_bfloat16* __restrict__ Vbf, const __hip_bfloat16* __restrict__ Qbf,
    const float* __restrict__ ksum, const float* __restrict__ carry,
    float* __restrict__ outp) {
  int b = blockIdx.x, c = blockIdx.y;
  int d0 = threadIdx.x * 4;
  size_t base = ((size_t)(b * Tt + c * CL) * Dd) + d0;
  f32x4 cr = *(const f32x4*)(carry + ((size_t)b * NC + c) * Dd + d0);
  float s0 = cr[0], s1 = cr[1], s2 = cr[2], s3 = cr[3];
  const float* kp = ksum + b * Tt + c * CL;
#pragma unroll 4
  for (int t = 0; t < CL; ++t) {
    size_t o = base + (size_t)t * Dd;
    u32x2 rv = __builtin_nontemporal_load((const u32x2*)(Vbf + o));
    u32x2 rq = __builtin_nontemporal_load((const u32x2*)(Qbf + o));
    float kv = kp[t];
    if (c == 0 && t == 0) kv = 0.f;
    s0 = s0 * GAMMA + kv * bflo(rv.x);
    s1 = s1 * GAMMA + kv * bfhi(rv.x);
    s2 = s2 * GAMMA + kv * bflo(rv.y);
    s3 = s3 * GAMMA + kv * bfhi(rv.y);
    f32x4 ov;
    ov[0] = bflo(rq.x) * s0;
    ov[1] = bfhi(rq.x) * s1;
    ov[2] = bflo(rq.y) * s2;
    ov[3] = bfhi(rq.y) * s3;
    __builtin_nontemporal_store(ov, (f32x4*)(outp + o));
  }
}

extern "C" void kernel_launch(void* const* d_in, const int* in_sizes, int n_in,
                              void* d_out, int out_size, void* d_ws, size_t ws_size,
                              hipStream_t stream) {
  (void)in_sizes; (void)n_in; (void)out_size; (void)ws_size;
  const float* xq = (const float*)d_in[0];
  const float* xk = (const float*)d_in[1];
  const float* xv = (const float*)d_in[2];
  const float* Wq = (const float*)d_in[3];
  const float* Wk = (const float*)d_in[4];
  const float* Wv = (const float*)d_in[5];
  float* outp = (float*)d_out;

  char* ws = (char*)d_ws;
  size_t off = 0;
  auto alloc = [&](size_t bytes) {
    char* p = ws + off;
    off += (bytes + 255) & ~(size_t)255;
    return p;
  };
  __hip_bfloat16* xq_bf = (__hip_bfloat16*)alloc((size_t)Mm * DIN * 2);
  __hip_bfloat16* xv_bf = (__hip_bfloat16*)alloc((size_t)Mm * DIN * 2);
  __hip_bfloat16* Wt    = (__hip_bfloat16*)alloc((size_t)2 * DIN * Dd * 2);
  __hip_bfloat16* Qbf   = (__hip_bfloat16*)alloc((size_t)Mm * Dd * 2);
  __hip_bfloat16* Vbf   = (__hip_bfloat16*)alloc((size_t)Mm * Dd * 2);
  float* wsum  = (float*)alloc((size_t)DIN * 4);
  float* ksum  = (float*)alloc((size_t)Mm * 4);
  float* E     = (float*)alloc((size_t)Bb * NC * Dd * 4);
  float* carry = (float*)alloc((size_t)Bb * NC * Dd * 4);

  double g = 1.0;
  for (int i = 0; i < CL; ++i) g *= (double)GAMMA;
  float gCL = (float)g;

  (void)hipFuncSetAttribute((const void*)gemm8_kernel,
                            hipFuncAttributeMaxDynamicSharedMemorySize, 131072);

  wsum_kernel<<<DIN / 4, 256, 0, stream>>>(Wk, wsum);
  wt_kernel<<<dim3(DIN / 32, Dd / 32, 2), dim3(32, 8), 0, stream>>>(Wq, Wv, Wt);
  cast_kernel<<<dim3(Mm * DIN / 16 / 256, 2), 256, 0, stream>>>(xq, xv, xq_bf, xv_bf);
  ksum_kernel<<<Mm / 4, 256, 0, stream>>>(xk, wsum, ksum);
  gemm8_kernel<<<256, 512, 131072, stream>>>(xq_bf, xv_bf, Wt, Qbf, Vbf);
  scanA_kernel<<<dim3(Bb, NC), 256, 0, stream>>>(Vbf, ksum, E);
  scanB_kernel<<<dim3(Bb, Dd / 256), 256, 0, stream>>>(E, carry, gCL);
  final_kernel<<<dim3(Bb, NC), 256, 0, stream>>>(Vbf, Qbf, ksum, carry, outp);
}